// Round 19
// baseline (222.991 us; speedup 1.0000x reference)
//
#include <hip/hip_runtime.h>
#include <hip/hip_bf16.h>

// ---------------- sizes ----------------
#define LSEQ 2048
#define DMODEL 768
#define DINNER 1536
#define DSTATE 16
#define DTRANK 48
#define XDBL_W (DTRANK + 2*DSTATE)   // 80
#define CHUNK 32
#define NCHUNK (LSEQ / CHUNK)        // 64
#define NDN (DINNER * DSTATE)        // 24576
#define FEPS 1.1920928955078125e-07f
#define SPLITK 8
#define OSPLIT 4                     // split-K factor for out_proj
#define LDST2 36                     // padded LDS row stride (floats) for 32-t tiles

typedef short bf16x8 __attribute__((ext_vector_type(8)));
typedef float f32x4 __attribute__((ext_vector_type(4)));
typedef unsigned short u16;

__device__ __forceinline__ u16 f2bf_rn(float f) {
    unsigned u = __float_as_uint(f);
    unsigned r = u + 0x7FFFu + ((u >> 16) & 1u);
    return (u16)(r >> 16);
}
__device__ __forceinline__ float bf2f(u16 h) {
    return __uint_as_float(((unsigned)h) << 16);
}

// quad_perm DPP lane exchange (full-rate VALU, no LDS pipe).
template<int CTRL>
__device__ __forceinline__ float qperm(float x) {
    return __int_as_float(__builtin_amdgcn_update_dpp(
        0, __float_as_int(x), CTRL, 0xF, 0xF, true));
}

// ---------------- fused fp32 -> bf16 hi/lo split for all three arrays ----------------
__global__ __launch_bounds__(256) void cvt_all(
    const float* __restrict__ w_in,  u16* __restrict__ wihi, u16* __restrict__ wilo, int n1,
    const float* __restrict__ w_out, u16* __restrict__ owhi, u16* __restrict__ owlo, int n2,
    const float* __restrict__ x,     u16* __restrict__ xhi,  u16* __restrict__ xlo)
{
    int i4 = (blockIdx.x * 256 + threadIdx.x) * 4;
    const float* src; u16* hi; u16* lo; int off;
    if (i4 < n1)            { src = w_in;  hi = wihi; lo = wilo; off = i4; }
    else if (i4 < n1 + n2)  { src = w_out; hi = owhi; lo = owlo; off = i4 - n1; }
    else                    { src = x;     hi = xhi;  lo = xlo;  off = i4 - n1 - n2; }
    float4 v = *(const float4*)&src[off];
    u16 h0 = f2bf_rn(v.x), h1 = f2bf_rn(v.y), h2 = f2bf_rn(v.z), h3 = f2bf_rn(v.w);
    u16 l0 = f2bf_rn(v.x - bf2f(h0));
    u16 l1 = f2bf_rn(v.y - bf2f(h1));
    u16 l2 = f2bf_rn(v.z - bf2f(h2));
    u16 l3 = f2bf_rn(v.w - bf2f(h3));
    *(ushort4*)&hi[off] = make_ushort4(h0, h1, h2, h3);
    *(ushort4*)&lo[off] = make_ushort4(l0, l1, l2, l3);
}

// ---------------- split-bf16 MFMA GEMM, double-buffered, 128xBN tile ----------------
// XCD-aware bijective blockIdx swizzle (grid size % 8 == 0 in all uses).
template<int BN>
__global__ __launch_bounds__(256) void mfma_gemm_tn(
    const u16* __restrict__ Ahi, const u16* __restrict__ Alo,
    const u16* __restrict__ Bhi, const u16* __restrict__ Blo,
    float* __restrict__ C, int ldc, int ldk, int Klen)
{
    constexpr int BUFSZ = 8192 + BN * 64;   // u16 per buffer (A: 8192, B: BN*64)
    constexpr int NJ = BN / 32;             // acc columns per wave
    __shared__ u16 lds[2 * BUFSZ];
    const int tid = threadIdx.x;
    const int wid = tid >> 6;
    const int lane = tid & 63;

    // XCD swizzle: hw-consecutive blocks -> contiguous logical chunk per XCD
    int nwg = gridDim.x * gridDim.y * gridDim.z;
    int lin = (blockIdx.z * gridDim.y + blockIdx.y) * gridDim.x + blockIdx.x;
    int q = nwg >> 3;
    int swz = (lin & 7) * q + (lin >> 3);
    int bx = swz % gridDim.x;
    int tmp = swz / gridDim.x;
    int by = tmp % gridDim.y;
    int bz = tmp / gridDim.y;

    const int m0 = bx * 128;
    const int n0 = by * BN;
    const int Koff = bz * Klen;

    const int st_subrow = lane >> 2;
    const int st_cphys = lane & 3;
    const u16* myplane = (wid == 0) ? Ahi : (wid == 1) ? Alo : (wid == 2) ? Bhi : Blo;
    const int rowbase = (wid < 2) ? m0 : n0;
    const int nIss = (wid < 2) ? 8 : (BN / 16);
    const int planeOff = (wid < 2) ? wid * 4096 : 8192 + (wid - 2) * (BN * 32);

    f32x4 acc[4][NJ] = {};
    const int wm = (wid >> 1) * 64;
    const int wn = (wid & 1) * (BN / 2);
    const int fr = lane & 15;
    const int fc = lane >> 4;
    const int nsteps = Klen / 32;

    auto stage = [&](int buf, int k0) {
#pragma unroll
        for (int j = 0; j < 8; ++j) {
            if (j < nIss) {
                int row = j * 16 + st_subrow;
                int clog = st_cphys ^ ((row >> 1) & 3);
                const u16* g = myplane + (size_t)(rowbase + row) * ldk + k0 + clog * 8;
                u16* l = &lds[buf * BUFSZ + planeOff + j * 512];
                __builtin_amdgcn_global_load_lds(
                    (const __attribute__((address_space(1))) unsigned int*)g,
                    (__attribute__((address_space(3))) unsigned int*)l, 16, 0, 0);
            }
        }
    };

    stage(0, Koff);
    int cur = 0;
    for (int t = 0; t < nsteps; ++t) {
        __syncthreads();
        if (t + 1 < nsteps) stage(cur ^ 1, Koff + (t + 1) * 32);

        bf16x8 ah[4], al[4], bh[NJ], bl[NJ];
        const bf16x8* L = (const bf16x8*)&lds[cur * BUFSZ];
#pragma unroll
        for (int mi = 0; mi < 4; ++mi) {
            int r = wm + mi * 16 + fr;
            int idx = r * 4 + (fc ^ ((r >> 1) & 3));
            ah[mi] = L[idx];
            al[mi] = L[512 + idx];
        }
#pragma unroll
        for (int nj = 0; nj < NJ; ++nj) {
            int r = wn + nj * 16 + fr;
            int idx = r * 4 + (fc ^ ((r >> 1) & 3));
            bh[nj] = L[1024 + idx];
            bl[nj] = L[1024 + BN * 4 + idx];
        }
#pragma unroll
        for (int mi = 0; mi < 4; ++mi)
#pragma unroll
            for (int nj = 0; nj < NJ; ++nj) {
                acc[mi][nj] = __builtin_amdgcn_mfma_f32_16x16x32_bf16(ah[mi], bh[nj], acc[mi][nj], 0, 0, 0);
                acc[mi][nj] = __builtin_amdgcn_mfma_f32_16x16x32_bf16(ah[mi], bl[nj], acc[mi][nj], 0, 0, 0);
                acc[mi][nj] = __builtin_amdgcn_mfma_f32_16x16x32_bf16(al[mi], bh[nj], acc[mi][nj], 0, 0, 0);
            }
        cur ^= 1;
    }

    float* Cz = C + (size_t)bz * LSEQ * ldc;
#pragma unroll
    for (int mi = 0; mi < 4; ++mi) {
        int row_b = m0 + wm + mi * 16 + (lane >> 4) * 4;
#pragma unroll
        for (int nj = 0; nj < NJ; ++nj) {
            int col = n0 + wn + nj * 16 + (lane & 15);
#pragma unroll
            for (int r = 0; r < 4; ++r)
                Cz[(size_t)(row_b + r) * ldc + col] = acc[mi][nj][r];
        }
    }
}

// deterministic 4-way partial reduce for out_proj
__global__ __launch_bounds__(256) void reduce4(
    const float* __restrict__ Ppart, float* __restrict__ out, int n)
{
    int i = (blockIdx.x * 256 + threadIdx.x) * 4;
    if (i >= n) return;
    float4 a0 = *(const float4*)&Ppart[i];
    float4 a1 = *(const float4*)&Ppart[(size_t)n + i];
    float4 a2 = *(const float4*)&Ppart[(size_t)2 * n + i];
    float4 a3 = *(const float4*)&Ppart[(size_t)3 * n + i];
    float4 r;
    r.x = ((a0.x + a1.x) + a2.x) + a3.x;
    r.y = ((a0.y + a1.y) + a2.y) + a3.y;
    r.z = ((a0.z + a1.z) + a2.z) + a3.z;
    r.w = ((a0.w + a1.w) + a2.w) + a3.w;
    *(float4*)&out[i] = r;
}

// ---------------- fp32 tiled GEMM (dt_proj) ----------------
template<int EPI>
__global__ __launch_bounds__(256) void gemm_tn(
    const float* __restrict__ A, int lda,
    const float* __restrict__ B, int ldb,
    float* __restrict__ C, int ldc,
    int M, int N, int K,
    const float* __restrict__ bias)
{
    __shared__ float As[16][64 + 4];
    __shared__ float Bs[16][64 + 4];
    const int tid = threadIdx.x;
    const int m0 = blockIdx.x * 64;
    const int n0 = blockIdx.y * 64;
    const int tx = tid & 15;
    const int ty = tid >> 4;
    const int lr = tid >> 4;
    const int lc = tid & 15;
    float acc[4][4] = {};

    for (int k0 = 0; k0 < K; k0 += 16) {
        const int k = k0 + lc;
#pragma unroll
        for (int i = 0; i < 4; ++i) {
            int m = m0 + lr + i * 16;
            As[lc][lr + i * 16] = (m < M) ? A[(size_t)m * lda + k] : 0.f;
        }
#pragma unroll
        for (int i = 0; i < 4; ++i) {
            int n = n0 + lr + i * 16;
            Bs[lc][lr + i * 16] = (n < N) ? B[(size_t)n * ldb + k] : 0.f;
        }
        __syncthreads();
#pragma unroll
        for (int kk = 0; kk < 16; ++kk) {
            float a[4], b[4];
#pragma unroll
            for (int i = 0; i < 4; ++i) a[i] = As[kk][ty * 4 + i];
#pragma unroll
            for (int j = 0; j < 4; ++j) b[j] = Bs[kk][tx * 4 + j];
#pragma unroll
            for (int i = 0; i < 4; ++i)
#pragma unroll
                for (int j = 0; j < 4; ++j)
                    acc[i][j] = fmaf(a[i], b[j], acc[i][j]);
        }
        __syncthreads();
    }

#pragma unroll
    for (int i = 0; i < 4; ++i) {
        int m = m0 + ty * 4 + i;
        if (m >= M) continue;
#pragma unroll
        for (int j = 0; j < 4; ++j) {
            int n = n0 + tx * 4 + j;
            if (n >= N) continue;
            float v = acc[i][j];
            if (EPI == 1) {
                v += bias[n];
                v = fmaxf(v, 0.f) + log1pf(expf(-fabsf(v)));
            }
            C[(size_t)m * ldc + n] = v;
        }
    }
}

// ---------------- fp32 split-K GEMM for x_proj ----------------
__global__ __launch_bounds__(256) void gemm_tn_splitk(
    const float* __restrict__ A, int lda,
    const float* __restrict__ B, int ldb,
    float* __restrict__ Cpart, int ldc,
    int M, int N, int Kchunk)
{
    __shared__ float As[16][64 + 4];
    __shared__ float Bs[16][64 + 4];
    const int tid = threadIdx.x;
    const int m0 = blockIdx.x * 64;
    const int n0 = blockIdx.y * 64;
    const int kb = blockIdx.z * Kchunk;
    const int tx = tid & 15;
    const int ty = tid >> 4;
    const int lr = tid >> 4;
    const int lc = tid & 15;
    float acc[4][4] = {};

    for (int k0 = kb; k0 < kb + Kchunk; k0 += 16) {
        const int k = k0 + lc;
#pragma unroll
        for (int i = 0; i < 4; ++i) {
            int m = m0 + lr + i * 16;
            As[lc][lr + i * 16] = (m < M) ? A[(size_t)m * lda + k] : 0.f;
        }
#pragma unroll
        for (int i = 0; i < 4; ++i) {
            int n = n0 + lr + i * 16;
            Bs[lc][lr + i * 16] = (n < N) ? B[(size_t)n * ldb + k] : 0.f;
        }
        __syncthreads();
#pragma unroll
        for (int kk = 0; kk < 16; ++kk) {
            float a[4], b[4];
#pragma unroll
            for (int i = 0; i < 4; ++i) a[i] = As[kk][ty * 4 + i];
#pragma unroll
            for (int j = 0; j < 4; ++j) b[j] = Bs[kk][tx * 4 + j];
#pragma unroll
            for (int i = 0; i < 4; ++i)
#pragma unroll
                for (int j = 0; j < 4; ++j)
                    acc[i][j] = fmaf(a[i], b[j], acc[i][j]);
        }
        __syncthreads();
    }

    float* Cs = Cpart + (size_t)blockIdx.z * M * ldc;
#pragma unroll
    for (int i = 0; i < 4; ++i) {
        int m = m0 + ty * 4 + i;
        if (m >= M) continue;
#pragma unroll
        for (int j = 0; j < 4; ++j) {
            int n = n0 + tx * 4 + j;
            if (n >= N) continue;
            Cs[(size_t)m * ldc + n] = acc[i][j];
        }
    }
}

__global__ __launch_bounds__(256) void splitk_reduce(
    const float* __restrict__ Ppart, float* __restrict__ out, int n)
{
    int i = blockIdx.x * 256 + threadIdx.x;
    if (i >= n) return;
    float s = 0.f;
#pragma unroll
    for (int z = 0; z < SPLITK; ++z) s += Ppart[(size_t)z * n + i];
    out[i] = s;
}

// ---------------- depthwise causal conv1d (width 4) + SiLU, 4 t-steps/thread ----------------
__global__ __launch_bounds__(256) void conv_silu_kernel(
    const float* __restrict__ xz,
    const float* __restrict__ conv_w,
    const float* __restrict__ conv_b,
    float* __restrict__ u)
{
    int idx = blockIdx.x * 256 + threadIdx.x;
    int d = idx % DINNER;
    int t0 = (idx / DINNER) * 4;
    float w[4];
#pragma unroll
    for (int j = 0; j < 4; ++j) w[j] = conv_w[d * 4 + j];
    const float b = conv_b[d];
    float xv[7];
#pragma unroll
    for (int k = 0; k < 7; ++k) {
        int s = t0 - 3 + k;
        xv[k] = (s >= 0) ? xz[(size_t)s * (2 * DINNER) + d] : 0.f;
    }
#pragma unroll
    for (int i = 0; i < 4; ++i) {
        float acc = b;
#pragma unroll
        for (int j = 0; j < 4; ++j)
            acc = fmaf(xv[i + j], w[j], acc);
        float sig = 1.f / (1.f + __expf(-acc));
        u[(size_t)(t0 + i) * DINNER + d] = acc * sig;
    }
}

// ================= chunked faithful scan (CHUNK=32, cumdt form) =================
__global__ __launch_bounds__(256) void dt_chunksum(
    const float* __restrict__ dtm, float* __restrict__ csum)
{
    int d = blockIdx.x * 256 + threadIdx.x;
    int c = blockIdx.y;
    size_t base = (size_t)c * CHUNK * DINNER + d;
    float s = 0.f;
#pragma unroll
    for (int i = 0; i < CHUNK; ++i)
        s += dtm[base + (size_t)i * DINNER];
    csum[(size_t)c * DINNER + d] = s;
}

__global__ __launch_bounds__(256) void cumdt_excl(float* __restrict__ csum)
{
    int d = blockIdx.x * 256 + threadIdx.x;
    float v[NCHUNK];
#pragma unroll
    for (int c = 0; c < NCHUNK; ++c)
        v[c] = csum[(size_t)c * DINNER + d];
    float run = 0.f;
#pragma unroll
    for (int c = 0; c < NCHUNK; ++c) {
        float t = v[c];
        v[c] = run;
        run += t;
    }
#pragma unroll
    for (int c = 0; c < NCHUNK; ++c)
        csum[(size_t)c * DINNER + d] = v[c];
}

template<int PROD>
__global__ __launch_bounds__(256) void scan_exclusive(float* __restrict__ buf)
{
    const int dn = blockIdx.x * 256 + threadIdx.x;
    float v[NCHUNK];
#pragma unroll
    for (int c = 0; c < NCHUNK; ++c)
        v[c] = buf[(size_t)c * NDN + dn];
    float run = PROD ? 1.f : 0.f;
#pragma unroll
    for (int c = 0; c < NCHUNK; ++c) {
        float t = v[c];
        v[c] = run;
        run = PROD ? run * t : run + t;
    }
#pragma unroll
    for (int c = 0; c < NCHUNK; ++c)
        buf[(size_t)c * NDN + dn] = v[c];
}

// Phase 3a: prefix-sum-exp form, seeded by cumdt.
__global__ __launch_bounds__(256) void scan_chunksum(
    const float* __restrict__ dtm,
    const float* __restrict__ u,
    const float* __restrict__ xdbl,
    const float* __restrict__ A_log,
    const float* __restrict__ cumdt,
    float* __restrict__ S)
{
    __shared__ float sdtT[16][LDST2], sduT[16][LDST2], sBT[16][LDST2];
    const int tid = threadIdx.x;
    const int d0 = blockIdx.x * 16;
    const int t0 = blockIdx.y * CHUNK;
    const int r = tid >> 4, c = tid & 15;
#pragma unroll
    for (int i = 0; i < 2; ++i) {
        int t = r + i * 16;
        size_t row = (size_t)(t0 + t);
        float dtv = dtm[row * DINNER + d0 + c];
        sdtT[c][t] = dtv;
        sduT[c][t] = dtv * u[row * DINNER + d0 + c];
        sBT[c][t]  = xdbl[row * XDBL_W + DTRANK + c];
    }
    __syncthreads();
    const int n = tid & 15, dl = tid >> 4;
    const float Acoef = -expf(A_log[(d0 + dl) * DSTATE + n]);
    float s = cumdt[(size_t)blockIdx.y * DINNER + d0 + dl];
    float acc = 0.f;
#pragma unroll
    for (int tb = 0; tb < CHUNK / 4; ++tb) {
        f32x4 dq  = *(const f32x4*)&sdtT[dl][tb * 4];
        f32x4 duq = *(const f32x4*)&sduT[dl][tb * 4];
        f32x4 bq  = *(const f32x4*)&sBT[n][tb * 4];
#pragma unroll
        for (int j = 0; j < 4; ++j) {
            s += dq[j];
            float p = __expf(Acoef * s);
            acc += __fdividef(duq[j] * bq[j], fmaxf(p, FEPS));
        }
    }
    S[(size_t)blockIdx.y * NDN + d0 * DSTATE + tid] = acc;
}

// Phase 3c+gate fused: dt/du staged (23040 B LDS); z,u read directly (64B-coalesced
// masked loads on the nq==0 lanes). y=(part+D*u)*silu(z) -> bf16 hi/lo.
__global__ __launch_bounds__(256) void scan_final(
    const float* __restrict__ dtm,
    const float* __restrict__ u,
    const float* __restrict__ xdbl,
    const float* __restrict__ A_log,
    const float* __restrict__ cumdt,
    const float* __restrict__ Gpre,
    const float* __restrict__ xz,     // z read from cols 1536..3071
    const float* __restrict__ Dvec,
    u16* __restrict__ yhi, u16* __restrict__ ylo)
{
    __shared__ float sdtT[64][LDST2], sduT[64][LDST2];
    __shared__ float sBT[16][LDST2], sCT[16][LDST2];
    const int tid = threadIdx.x;
    const int d0 = blockIdx.x * 64;
    const int t0 = blockIdx.y * CHUNK;

#pragma unroll
    for (int i = 0; i < 8; ++i) {
        int idx = i * 256 + tid;
        int dl = idx & 63, tl = idx >> 6;
        size_t row = (size_t)(t0 + tl);
        float dtv = dtm[row * DINNER + d0 + dl];
        sdtT[dl][tl] = dtv;
        sduT[dl][tl] = dtv * u[row * DINNER + d0 + dl];
    }
#pragma unroll
    for (int i = 0; i < 2; ++i) {
        int idx = i * 256 + tid;
        int n = idx & 15, tl = idx >> 4;
        size_t row = (size_t)(t0 + tl);
        sBT[n][tl] = xdbl[row * XDBL_W + DTRANK + n];
        sCT[n][tl] = xdbl[row * XDBL_W + DTRANK + DSTATE + n];
    }
    __syncthreads();

    const int lane = tid & 63, wid = tid >> 6;
    const int dloc = wid * 16 + (lane >> 2);
    const int d = d0 + dloc;
    const int nq = lane & 3;

    f32x4 Ar = *(const f32x4*)&A_log[d * DSTATE + nq * 4];
    float Ac[4] = {-expf(Ar[0]), -expf(Ar[1]), -expf(Ar[2]), -expf(Ar[3])};
    size_t pgbase = (size_t)blockIdx.y * NDN + (size_t)d * DSTATE + nq * 4;
    f32x4 g = *(const f32x4*)&Gpre[pgbase];
    float s = cumdt[(size_t)blockIdx.y * DINNER + d];
    const float Dd = Dvec[d];

#pragma unroll
    for (int tb = 0; tb < CHUNK / 4; ++tb) {
        f32x4 dq  = *(const f32x4*)&sdtT[dloc][tb * 4];
        f32x4 duq = *(const f32x4*)&sduT[dloc][tb * 4];
        f32x4 b0 = *(const f32x4*)&sBT[nq * 4 + 0][tb * 4];
        f32x4 b1 = *(const f32x4*)&sBT[nq * 4 + 1][tb * 4];
        f32x4 b2 = *(const f32x4*)&sBT[nq * 4 + 2][tb * 4];
        f32x4 b3 = *(const f32x4*)&sBT[nq * 4 + 3][tb * 4];
        f32x4 c0 = *(const f32x4*)&sCT[nq * 4 + 0][tb * 4];
        f32x4 c1 = *(const f32x4*)&sCT[nq * 4 + 1][tb * 4];
        f32x4 c2 = *(const f32x4*)&sCT[nq * 4 + 2][tb * 4];
        f32x4 c3 = *(const f32x4*)&sCT[nq * 4 + 3][tb * 4];
#pragma unroll
        for (int j = 0; j < 4; ++j) {
            float duv = duq[j];
            s += dq[j];
            float p0 = __expf(Ac[0] * s);
            float p1 = __expf(Ac[1] * s);
            float p2 = __expf(Ac[2] * s);
            float p3 = __expf(Ac[3] * s);
            g[0] += __fdividef(duv * b0[j], fmaxf(p0, FEPS));
            g[1] += __fdividef(duv * b1[j], fmaxf(p1, FEPS));
            g[2] += __fdividef(duv * b2[j], fmaxf(p2, FEPS));
            g[3] += __fdividef(duv * b3[j], fmaxf(p3, FEPS));
            float part = (g[0] * p0) * c0[j];
            part = fmaf(g[1] * p1, c1[j], part);
            part = fmaf(g[2] * p2, c2[j], part);
            part = fmaf(g[3] * p3, c3[j], part);
            part += qperm<0xB1>(part);
            part += qperm<0x4E>(part);
            if (nq == 0) {
                size_t row = (size_t)(t0 + tb * 4 + j);
                float zv = xz[row * (size_t)(2 * DINNER) + DINNER + d];
                float uv = u[row * DINNER + d];
                float sig = 1.f / (1.f + __expf(-zv));
                float yv = (part + Dd * uv) * (zv * sig);
                u16 h = f2bf_rn(yv);
                u16 l = f2bf_rn(yv - bf2f(h));
                size_t o = row * DINNER + d;
                yhi[o] = h;
                ylo[o] = l;
            }
        }
    }
}

// ---------------- launch ----------------
extern "C" void kernel_launch(void* const* d_in, const int* in_sizes, int n_in,
                              void* d_out, int out_size, void* d_ws, size_t ws_size,
                              hipStream_t stream) {
    const float* x          = (const float*)d_in[0];
    const float* in_proj_w  = (const float*)d_in[1];
    const float* conv_w     = (const float*)d_in[2];
    const float* conv_b     = (const float*)d_in[3];
    const float* x_proj_w   = (const float*)d_in[4];
    const float* dt_proj_w  = (const float*)d_in[5];
    const float* dt_proj_b  = (const float*)d_in[6];
    const float* A_log      = (const float*)d_in[7];
    const float* Dvec       = (const float*)d_in[8];
    const float* out_proj_w = (const float*)d_in[9];
    float* out = (float*)d_out;

    char* w = (char*)d_ws;
    auto alloc = [&](size_t bytes) { char* p = w; w += (bytes + 255) & ~(size_t)255; return p; };

    float* xz    = (float*)alloc((size_t)LSEQ * 2 * DINNER * 4);
    float* u     = (float*)alloc((size_t)LSEQ * DINNER * 4);
    float* xdbl  = (float*)alloc((size_t)LSEQ * XDBL_W * 4);
    float* dtb   = (float*)alloc((size_t)LSEQ * DINNER * 4);
    float* csum  = (float*)alloc((size_t)NCHUNK * DINNER * 4);
    float* S     = (float*)alloc((size_t)NCHUNK * NDN * 4);
    float* Ppart = (float*)alloc((size_t)SPLITK * LSEQ * XDBL_W * 4);
    u16* xhi  = (u16*)alloc((size_t)LSEQ * DMODEL * 2);
    u16* xlo  = (u16*)alloc((size_t)LSEQ * DMODEL * 2);
    u16* wihi = (u16*)alloc((size_t)2 * DINNER * DMODEL * 2);
    u16* wilo = (u16*)alloc((size_t)2 * DINNER * DMODEL * 2);
    u16* owhi = (u16*)alloc((size_t)DMODEL * DINNER * 2);
    u16* owlo = (u16*)alloc((size_t)DMODEL * DINNER * 2);
    u16* yhi  = (u16*)alloc((size_t)LSEQ * DINNER * 2);
    u16* ylo  = (u16*)alloc((size_t)LSEQ * DINNER * 2);
    float* opart = u;   // out_proj partials alias u..S (dead after scan_final)

    dim3 blk(256);

    // 0. fused conversions to bf16 hi/lo (one launch)
    {
        int n1 = 2 * DINNER * DMODEL;
        int n2 = DMODEL * DINNER;
        int n3 = LSEQ * DMODEL;
        cvt_all<<<(n1 + n2 + n3) / 1024, blk, 0, stream>>>(
            in_proj_w, wihi, wilo, n1, out_proj_w, owhi, owlo, n2, x, xhi, xlo);
    }

    // 1. xz = x @ in_proj_w.T   (M=2048, N=3072, K=768), 128x128 dbuf MFMA + XCD swizzle
    mfma_gemm_tn<128><<<dim3(LSEQ / 128, (2 * DINNER) / 128, 1), blk, 0, stream>>>(
        xhi, xlo, wihi, wilo, xz, 2 * DINNER, DMODEL, DMODEL);

    // 2. u = silu(depthwise_conv(xh) + b), 4 t/thread
    conv_silu_kernel<<<(LSEQ / 4) * DINNER / 256, blk, 0, stream>>>(xz, conv_w, conv_b, u);

    // 3. x_dbl = u @ x_proj_w.T (split-K fp32, deterministic reduce)
    gemm_tn_splitk<<<dim3(LSEQ / 64, (XDBL_W + 63) / 64, SPLITK), blk, 0, stream>>>(
        u, DINNER, x_proj_w, DINNER, Ppart, XDBL_W, LSEQ, XDBL_W, DINNER / SPLITK);
    splitk_reduce<<<(LSEQ * XDBL_W + 255) / 256, blk, 0, stream>>>(Ppart, xdbl, LSEQ * XDBL_W);

    // 4. dt = softplus(x_dbl[:, :48] @ dt_proj_w.T + dt_proj_b)
    gemm_tn<1><<<dim3(LSEQ / 64, DINNER / 64), blk, 0, stream>>>(
        xdbl, XDBL_W, dt_proj_w, DTRANK, dtb, DINNER, LSEQ, DINNER, DTRANK, dt_proj_b);

    // 5. chunked faithful selective scan (cumdt form) + fused gate -> y bf16 hi/lo
    dt_chunksum<<<dim3(DINNER / 256, NCHUNK), blk, 0, stream>>>(dtb, csum);
    cumdt_excl<<<DINNER / 256, blk, 0, stream>>>(csum);
    scan_chunksum<<<dim3(DINNER / 16, NCHUNK), blk, 0, stream>>>(dtb, u, xdbl, A_log, csum, S);
    scan_exclusive<0><<<NDN / 256, blk, 0, stream>>>(S);
    scan_final<<<dim3(DINNER / 64, NCHUNK), blk, 0, stream>>>(
        dtb, u, xdbl, A_log, csum, S, xz, Dvec, yhi, ylo);

    // 6. out = y @ out_proj_w.T (128x64 tiles, split-K=4 + reduce) + XCD swizzle
    mfma_gemm_tn<64><<<dim3(LSEQ / 128, DMODEL / 64, OSPLIT), blk, 0, stream>>>(
        yhi, ylo, owhi, owlo, opart, DMODEL, DINNER, DINNER / OSPLIT);
    reduce4<<<(LSEQ * DMODEL) / 1024, blk, 0, stream>>>(opart, out, LSEQ * DMODEL);
}

// Round 21
// 215.530 us; speedup vs baseline: 1.0346x; 1.0346x over previous
//
#include <hip/hip_runtime.h>
#include <hip/hip_bf16.h>

// ---------------- sizes ----------------
#define LSEQ 2048
#define DMODEL 768
#define DINNER 1536
#define DSTATE 16
#define DTRANK 48
#define XDBL_W (DTRANK + 2*DSTATE)   // 80
#define CHUNK 32
#define NCHUNK (LSEQ / CHUNK)        // 64
#define NDN (DINNER * DSTATE)        // 24576
#define FEPS 1.1920928955078125e-07f
#define SPLITK 8
#define OSPLIT 4                     // split-K factor for out_proj
#define LDST2 36                     // padded LDS row stride (floats) for 32-t tiles

typedef short bf16x8 __attribute__((ext_vector_type(8)));
typedef float f32x4 __attribute__((ext_vector_type(4)));
typedef unsigned short u16;

__device__ __forceinline__ u16 f2bf_rn(float f) {
    unsigned u = __float_as_uint(f);
    unsigned r = u + 0x7FFFu + ((u >> 16) & 1u);
    return (u16)(r >> 16);
}
__device__ __forceinline__ float bf2f(u16 h) {
    return __uint_as_float(((unsigned)h) << 16);
}

// quad_perm DPP lane exchange (full-rate VALU, no LDS pipe).
template<int CTRL>
__device__ __forceinline__ float qperm(float x) {
    return __int_as_float(__builtin_amdgcn_update_dpp(
        0, __float_as_int(x), CTRL, 0xF, 0xF, true));
}

// ---------------- fused fp32 -> bf16 hi/lo split for all three arrays ----------------
__global__ __launch_bounds__(256) void cvt_all(
    const float* __restrict__ w_in,  u16* __restrict__ wihi, u16* __restrict__ wilo, int n1,
    const float* __restrict__ w_out, u16* __restrict__ owhi, u16* __restrict__ owlo, int n2,
    const float* __restrict__ x,     u16* __restrict__ xhi,  u16* __restrict__ xlo)
{
    int i4 = (blockIdx.x * 256 + threadIdx.x) * 4;
    const float* src; u16* hi; u16* lo; int off;
    if (i4 < n1)            { src = w_in;  hi = wihi; lo = wilo; off = i4; }
    else if (i4 < n1 + n2)  { src = w_out; hi = owhi; lo = owlo; off = i4 - n1; }
    else                    { src = x;     hi = xhi;  lo = xlo;  off = i4 - n1 - n2; }
    float4 v = *(const float4*)&src[off];
    u16 h0 = f2bf_rn(v.x), h1 = f2bf_rn(v.y), h2 = f2bf_rn(v.z), h3 = f2bf_rn(v.w);
    u16 l0 = f2bf_rn(v.x - bf2f(h0));
    u16 l1 = f2bf_rn(v.y - bf2f(h1));
    u16 l2 = f2bf_rn(v.z - bf2f(h2));
    u16 l3 = f2bf_rn(v.w - bf2f(h3));
    *(ushort4*)&hi[off] = make_ushort4(h0, h1, h2, h3);
    *(ushort4*)&lo[off] = make_ushort4(l0, l1, l2, l3);
}

// ---------------- split-bf16 MFMA GEMM, double-buffered, 128xBN tile ----------------
// XCD-aware bijective blockIdx swizzle (grid size % 8 == 0 in all uses).
template<int BN>
__global__ __launch_bounds__(256) void mfma_gemm_tn(
    const u16* __restrict__ Ahi, const u16* __restrict__ Alo,
    const u16* __restrict__ Bhi, const u16* __restrict__ Blo,
    float* __restrict__ C, int ldc, int ldk, int Klen)
{
    constexpr int BUFSZ = 8192 + BN * 64;   // u16 per buffer (A: 8192, B: BN*64)
    constexpr int NJ = BN / 32;             // acc columns per wave
    __shared__ u16 lds[2 * BUFSZ];
    const int tid = threadIdx.x;
    const int wid = tid >> 6;
    const int lane = tid & 63;

    // XCD swizzle: hw-consecutive blocks -> contiguous logical chunk per XCD
    int nwg = gridDim.x * gridDim.y * gridDim.z;
    int lin = (blockIdx.z * gridDim.y + blockIdx.y) * gridDim.x + blockIdx.x;
    int q = nwg >> 3;
    int swz = (lin & 7) * q + (lin >> 3);
    int bx = swz % gridDim.x;
    int tmp = swz / gridDim.x;
    int by = tmp % gridDim.y;
    int bz = tmp / gridDim.y;

    const int m0 = bx * 128;
    const int n0 = by * BN;
    const int Koff = bz * Klen;

    const int st_subrow = lane >> 2;
    const int st_cphys = lane & 3;
    const u16* myplane = (wid == 0) ? Ahi : (wid == 1) ? Alo : (wid == 2) ? Bhi : Blo;
    const int rowbase = (wid < 2) ? m0 : n0;
    const int nIss = (wid < 2) ? 8 : (BN / 16);
    const int planeOff = (wid < 2) ? wid * 4096 : 8192 + (wid - 2) * (BN * 32);

    f32x4 acc[4][NJ] = {};
    const int wm = (wid >> 1) * 64;
    const int wn = (wid & 1) * (BN / 2);
    const int fr = lane & 15;
    const int fc = lane >> 4;
    const int nsteps = Klen / 32;

    auto stage = [&](int buf, int k0) {
#pragma unroll
        for (int j = 0; j < 8; ++j) {
            if (j < nIss) {
                int row = j * 16 + st_subrow;
                int clog = st_cphys ^ ((row >> 1) & 3);
                const u16* g = myplane + (size_t)(rowbase + row) * ldk + k0 + clog * 8;
                u16* l = &lds[buf * BUFSZ + planeOff + j * 512];
                __builtin_amdgcn_global_load_lds(
                    (const __attribute__((address_space(1))) unsigned int*)g,
                    (__attribute__((address_space(3))) unsigned int*)l, 16, 0, 0);
            }
        }
    };

    stage(0, Koff);
    int cur = 0;
    for (int t = 0; t < nsteps; ++t) {
        __syncthreads();
        if (t + 1 < nsteps) stage(cur ^ 1, Koff + (t + 1) * 32);

        bf16x8 ah[4], al[4], bh[NJ], bl[NJ];
        const bf16x8* L = (const bf16x8*)&lds[cur * BUFSZ];
#pragma unroll
        for (int mi = 0; mi < 4; ++mi) {
            int r = wm + mi * 16 + fr;
            int idx = r * 4 + (fc ^ ((r >> 1) & 3));
            ah[mi] = L[idx];
            al[mi] = L[512 + idx];
        }
#pragma unroll
        for (int nj = 0; nj < NJ; ++nj) {
            int r = wn + nj * 16 + fr;
            int idx = r * 4 + (fc ^ ((r >> 1) & 3));
            bh[nj] = L[1024 + idx];
            bl[nj] = L[1024 + BN * 4 + idx];
        }
#pragma unroll
        for (int mi = 0; mi < 4; ++mi)
#pragma unroll
            for (int nj = 0; nj < NJ; ++nj) {
                acc[mi][nj] = __builtin_amdgcn_mfma_f32_16x16x32_bf16(ah[mi], bh[nj], acc[mi][nj], 0, 0, 0);
                acc[mi][nj] = __builtin_amdgcn_mfma_f32_16x16x32_bf16(ah[mi], bl[nj], acc[mi][nj], 0, 0, 0);
                acc[mi][nj] = __builtin_amdgcn_mfma_f32_16x16x32_bf16(al[mi], bh[nj], acc[mi][nj], 0, 0, 0);
            }
        cur ^= 1;
    }

    float* Cz = C + (size_t)bz * LSEQ * ldc;
#pragma unroll
    for (int mi = 0; mi < 4; ++mi) {
        int row_b = m0 + wm + mi * 16 + (lane >> 4) * 4;
#pragma unroll
        for (int nj = 0; nj < NJ; ++nj) {
            int col = n0 + wn + nj * 16 + (lane & 15);
#pragma unroll
            for (int r = 0; r < 4; ++r)
                Cz[(size_t)(row_b + r) * ldc + col] = acc[mi][nj][r];
        }
    }
}

// deterministic 4-way partial reduce for out_proj
__global__ __launch_bounds__(256) void reduce4(
    const float* __restrict__ Ppart, float* __restrict__ out, int n)
{
    int i = (blockIdx.x * 256 + threadIdx.x) * 4;
    if (i >= n) return;
    float4 a0 = *(const float4*)&Ppart[i];
    float4 a1 = *(const float4*)&Ppart[(size_t)n + i];
    float4 a2 = *(const float4*)&Ppart[(size_t)2 * n + i];
    float4 a3 = *(const float4*)&Ppart[(size_t)3 * n + i];
    float4 r;
    r.x = ((a0.x + a1.x) + a2.x) + a3.x;
    r.y = ((a0.y + a1.y) + a2.y) + a3.y;
    r.z = ((a0.z + a1.z) + a2.z) + a3.z;
    r.w = ((a0.w + a1.w) + a2.w) + a3.w;
    *(float4*)&out[i] = r;
}

// ---------------- fp32 tiled GEMM (dt_proj) ----------------
template<int EPI>
__global__ __launch_bounds__(256) void gemm_tn(
    const float* __restrict__ A, int lda,
    const float* __restrict__ B, int ldb,
    float* __restrict__ C, int ldc,
    int M, int N, int K,
    const float* __restrict__ bias)
{
    __shared__ float As[16][64 + 4];
    __shared__ float Bs[16][64 + 4];
    const int tid = threadIdx.x;
    const int m0 = blockIdx.x * 64;
    const int n0 = blockIdx.y * 64;
    const int tx = tid & 15;
    const int ty = tid >> 4;
    const int lr = tid >> 4;
    const int lc = tid & 15;
    float acc[4][4] = {};

    for (int k0 = 0; k0 < K; k0 += 16) {
        const int k = k0 + lc;
#pragma unroll
        for (int i = 0; i < 4; ++i) {
            int m = m0 + lr + i * 16;
            As[lc][lr + i * 16] = (m < M) ? A[(size_t)m * lda + k] : 0.f;
        }
#pragma unroll
        for (int i = 0; i < 4; ++i) {
            int n = n0 + lr + i * 16;
            Bs[lc][lr + i * 16] = (n < N) ? B[(size_t)n * ldb + k] : 0.f;
        }
        __syncthreads();
#pragma unroll
        for (int kk = 0; kk < 16; ++kk) {
            float a[4], b[4];
#pragma unroll
            for (int i = 0; i < 4; ++i) a[i] = As[kk][ty * 4 + i];
#pragma unroll
            for (int j = 0; j < 4; ++j) b[j] = Bs[kk][tx * 4 + j];
#pragma unroll
            for (int i = 0; i < 4; ++i)
#pragma unroll
                for (int j = 0; j < 4; ++j)
                    acc[i][j] = fmaf(a[i], b[j], acc[i][j]);
        }
        __syncthreads();
    }

#pragma unroll
    for (int i = 0; i < 4; ++i) {
        int m = m0 + ty * 4 + i;
        if (m >= M) continue;
#pragma unroll
        for (int j = 0; j < 4; ++j) {
            int n = n0 + tx * 4 + j;
            if (n >= N) continue;
            float v = acc[i][j];
            if (EPI == 1) {
                v += bias[n];
                v = fmaxf(v, 0.f) + log1pf(expf(-fabsf(v)));
            }
            C[(size_t)m * ldc + n] = v;
        }
    }
}

// ---------------- fp32 split-K GEMM for x_proj ----------------
__global__ __launch_bounds__(256) void gemm_tn_splitk(
    const float* __restrict__ A, int lda,
    const float* __restrict__ B, int ldb,
    float* __restrict__ Cpart, int ldc,
    int M, int N, int Kchunk)
{
    __shared__ float As[16][64 + 4];
    __shared__ float Bs[16][64 + 4];
    const int tid = threadIdx.x;
    const int m0 = blockIdx.x * 64;
    const int n0 = blockIdx.y * 64;
    const int kb = blockIdx.z * Kchunk;
    const int tx = tid & 15;
    const int ty = tid >> 4;
    const int lr = tid >> 4;
    const int lc = tid & 15;
    float acc[4][4] = {};

    for (int k0 = kb; k0 < kb + Kchunk; k0 += 16) {
        const int k = k0 + lc;
#pragma unroll
        for (int i = 0; i < 4; ++i) {
            int m = m0 + lr + i * 16;
            As[lc][lr + i * 16] = (m < M) ? A[(size_t)m * lda + k] : 0.f;
        }
#pragma unroll
        for (int i = 0; i < 4; ++i) {
            int n = n0 + lr + i * 16;
            Bs[lc][lr + i * 16] = (n < N) ? B[(size_t)n * ldb + k] : 0.f;
        }
        __syncthreads();
#pragma unroll
        for (int kk = 0; kk < 16; ++kk) {
            float a[4], b[4];
#pragma unroll
            for (int i = 0; i < 4; ++i) a[i] = As[kk][ty * 4 + i];
#pragma unroll
            for (int j = 0; j < 4; ++j) b[j] = Bs[kk][tx * 4 + j];
#pragma unroll
            for (int i = 0; i < 4; ++i)
#pragma unroll
                for (int j = 0; j < 4; ++j)
                    acc[i][j] = fmaf(a[i], b[j], acc[i][j]);
        }
        __syncthreads();
    }

    float* Cs = Cpart + (size_t)blockIdx.z * M * ldc;
#pragma unroll
    for (int i = 0; i < 4; ++i) {
        int m = m0 + ty * 4 + i;
        if (m >= M) continue;
#pragma unroll
        for (int j = 0; j < 4; ++j) {
            int n = n0 + tx * 4 + j;
            if (n >= N) continue;
            Cs[(size_t)m * ldc + n] = acc[i][j];
        }
    }
}

__global__ __launch_bounds__(256) void splitk_reduce(
    const float* __restrict__ Ppart, float* __restrict__ out, int n)
{
    int i = blockIdx.x * 256 + threadIdx.x;
    if (i >= n) return;
    float s = 0.f;
#pragma unroll
    for (int z = 0; z < SPLITK; ++z) s += Ppart[(size_t)z * n + i];
    out[i] = s;
}

// ---------------- depthwise causal conv1d (width 4) + SiLU, 4 t-steps/thread ----------------
__global__ __launch_bounds__(256) void conv_silu_kernel(
    const float* __restrict__ xz,
    const float* __restrict__ conv_w,
    const float* __restrict__ conv_b,
    float* __restrict__ u)
{
    int idx = blockIdx.x * 256 + threadIdx.x;
    int d = idx % DINNER;
    int t0 = (idx / DINNER) * 4;
    float w[4];
#pragma unroll
    for (int j = 0; j < 4; ++j) w[j] = conv_w[d * 4 + j];
    const float b = conv_b[d];
    float xv[7];
#pragma unroll
    for (int k = 0; k < 7; ++k) {
        int s = t0 - 3 + k;
        xv[k] = (s >= 0) ? xz[(size_t)s * (2 * DINNER) + d] : 0.f;
    }
#pragma unroll
    for (int i = 0; i < 4; ++i) {
        float acc = b;
#pragma unroll
        for (int j = 0; j < 4; ++j)
            acc = fmaf(xv[i + j], w[j], acc);
        float sig = 1.f / (1.f + __expf(-acc));
        u[(size_t)(t0 + i) * DINNER + d] = acc * sig;
    }
}

// ================= chunked faithful scan (CHUNK=32, cumdt form) =================
// Per-chunk dt sums (d-only, 16x less work than old chunkprod).
__global__ __launch_bounds__(256) void dt_chunksum(
    const float* __restrict__ dtm, float* __restrict__ csum)
{
    int d = blockIdx.x * 256 + threadIdx.x;          // gridDim.x = DINNER/256
    int c = blockIdx.y;
    size_t base = (size_t)c * CHUNK * DINNER + d;
    float s = 0.f;
#pragma unroll
    for (int i = 0; i < CHUNK; ++i)
        s += dtm[base + (size_t)i * DINNER];
    csum[(size_t)c * DINNER + d] = s;
}

// Exclusive sum over chunks of csum (register-staged).
__global__ __launch_bounds__(256) void cumdt_excl(float* __restrict__ csum)
{
    int d = blockIdx.x * 256 + threadIdx.x;
    float v[NCHUNK];
#pragma unroll
    for (int c = 0; c < NCHUNK; ++c)
        v[c] = csum[(size_t)c * DINNER + d];
    float run = 0.f;
#pragma unroll
    for (int c = 0; c < NCHUNK; ++c) {
        float t = v[c];
        v[c] = run;
        run += t;
    }
#pragma unroll
    for (int c = 0; c < NCHUNK; ++c)
        csum[(size_t)c * DINNER + d] = v[c];
}

// Register-staged exclusive scan over chunks for S (g), n-dependent.
template<int PROD>
__global__ __launch_bounds__(256) void scan_exclusive(float* __restrict__ buf)
{
    const int dn = blockIdx.x * 256 + threadIdx.x;
    float v[NCHUNK];
#pragma unroll
    for (int c = 0; c < NCHUNK; ++c)
        v[c] = buf[(size_t)c * NDN + dn];
    float run = PROD ? 1.f : 0.f;
#pragma unroll
    for (int c = 0; c < NCHUNK; ++c) {
        float t = v[c];
        v[c] = run;
        run = PROD ? run * t : run + t;
    }
#pragma unroll
    for (int c = 0; c < NCHUNK; ++c)
        buf[(size_t)c * NDN + dn] = v[c];
}

// Phase 3a: prefix-sum-exp form, seeded by cumdt (p = exp(Acoef*(cumdt + local))).
__global__ __launch_bounds__(256) void scan_chunksum(
    const float* __restrict__ dtm,
    const float* __restrict__ u,
    const float* __restrict__ xdbl,
    const float* __restrict__ A_log,
    const float* __restrict__ cumdt,
    float* __restrict__ S)
{
    __shared__ float sdtT[16][LDST2], sduT[16][LDST2], sBT[16][LDST2];
    const int tid = threadIdx.x;
    const int d0 = blockIdx.x * 16;
    const int t0 = blockIdx.y * CHUNK;
    const int r = tid >> 4, c = tid & 15;
#pragma unroll
    for (int i = 0; i < 2; ++i) {
        int t = r + i * 16;
        size_t row = (size_t)(t0 + t);
        float dtv = dtm[row * DINNER + d0 + c];
        sdtT[c][t] = dtv;
        sduT[c][t] = dtv * u[row * DINNER + d0 + c];
        sBT[c][t]  = xdbl[row * XDBL_W + DTRANK + c];
    }
    __syncthreads();
    const int n = tid & 15, dl = tid >> 4;
    const float Acoef = -expf(A_log[(d0 + dl) * DSTATE + n]);
    float s = cumdt[(size_t)blockIdx.y * DINNER + d0 + dl];
    float acc = 0.f;
#pragma unroll
    for (int tb = 0; tb < CHUNK / 4; ++tb) {
        f32x4 dq  = *(const f32x4*)&sdtT[dl][tb * 4];
        f32x4 duq = *(const f32x4*)&sduT[dl][tb * 4];
        f32x4 bq  = *(const f32x4*)&sBT[n][tb * 4];
#pragma unroll
        for (int j = 0; j < 4; ++j) {
            s += dq[j];
            float p = __expf(Acoef * s);
            acc += __fdividef(duq[j] * bq[j], fmaxf(p, FEPS));
        }
    }
    S[(size_t)blockIdx.y * NDN + d0 * DSTATE + tid] = acc;
}

// Phase 3c: 4-n-per-lane + cumdt-seeded prefix-sum-exp + quad-DPP reduction.
__global__ __launch_bounds__(256) void scan_final(
    const float* __restrict__ dtm,
    const float* __restrict__ u,
    const float* __restrict__ xdbl,
    const float* __restrict__ A_log,
    const float* __restrict__ cumdt,
    const float* __restrict__ Gpre,
    float* __restrict__ xz)           // part written to cols 0..1535
{
    __shared__ float sdtT[64][LDST2], sduT[64][LDST2];
    __shared__ float sBT[16][LDST2], sCT[16][LDST2];
    const int tid = threadIdx.x;
    const int d0 = blockIdx.x * 64;
    const int t0 = blockIdx.y * CHUNK;

#pragma unroll
    for (int i = 0; i < 8; ++i) {
        int idx = i * 256 + tid;
        int dl = idx & 63, tl = idx >> 6;
        size_t row = (size_t)(t0 + tl);
        float dtv = dtm[row * DINNER + d0 + dl];
        sdtT[dl][tl] = dtv;
        sduT[dl][tl] = dtv * u[row * DINNER + d0 + dl];
    }
#pragma unroll
    for (int i = 0; i < 2; ++i) {
        int idx = i * 256 + tid;
        int n = idx & 15, tl = idx >> 4;
        size_t row = (size_t)(t0 + tl);
        sBT[n][tl] = xdbl[row * XDBL_W + DTRANK + n];
        sCT[n][tl] = xdbl[row * XDBL_W + DTRANK + DSTATE + n];
    }
    __syncthreads();

    const int lane = tid & 63, wid = tid >> 6;
    const int dloc = wid * 16 + (lane >> 2);
    const int d = d0 + dloc;
    const int nq = lane & 3;

    f32x4 Ar = *(const f32x4*)&A_log[d * DSTATE + nq * 4];
    float Ac[4] = {-expf(Ar[0]), -expf(Ar[1]), -expf(Ar[2]), -expf(Ar[3])};
    size_t pgbase = (size_t)blockIdx.y * NDN + (size_t)d * DSTATE + nq * 4;
    f32x4 g = *(const f32x4*)&Gpre[pgbase];
    float s = cumdt[(size_t)blockIdx.y * DINNER + d];

#pragma unroll
    for (int tb = 0; tb < CHUNK / 4; ++tb) {
        f32x4 dq  = *(const f32x4*)&sdtT[dloc][tb * 4];
        f32x4 duq = *(const f32x4*)&sduT[dloc][tb * 4];
        f32x4 b0 = *(const f32x4*)&sBT[nq * 4 + 0][tb * 4];
        f32x4 b1 = *(const f32x4*)&sBT[nq * 4 + 1][tb * 4];
        f32x4 b2 = *(const f32x4*)&sBT[nq * 4 + 2][tb * 4];
        f32x4 b3 = *(const f32x4*)&sBT[nq * 4 + 3][tb * 4];
        f32x4 c0 = *(const f32x4*)&sCT[nq * 4 + 0][tb * 4];
        f32x4 c1 = *(const f32x4*)&sCT[nq * 4 + 1][tb * 4];
        f32x4 c2 = *(const f32x4*)&sCT[nq * 4 + 2][tb * 4];
        f32x4 c3 = *(const f32x4*)&sCT[nq * 4 + 3][tb * 4];
#pragma unroll
        for (int j = 0; j < 4; ++j) {
            float duv = duq[j];
            s += dq[j];
            float p0 = __expf(Ac[0] * s);
            float p1 = __expf(Ac[1] * s);
            float p2 = __expf(Ac[2] * s);
            float p3 = __expf(Ac[3] * s);
            g[0] += __fdividef(duv * b0[j], fmaxf(p0, FEPS));
            g[1] += __fdividef(duv * b1[j], fmaxf(p1, FEPS));
            g[2] += __fdividef(duv * b2[j], fmaxf(p2, FEPS));
            g[3] += __fdividef(duv * b3[j], fmaxf(p3, FEPS));
            float part = (g[0] * p0) * c0[j];
            part = fmaf(g[1] * p1, c1[j], part);
            part = fmaf(g[2] * p2, c2[j], part);
            part = fmaf(g[3] * p3, c3[j], part);
            part += qperm<0xB1>(part);
            part += qperm<0x4E>(part);
            if (nq == 0)
                xz[(size_t)(t0 + tb * 4 + j) * (2 * DINNER) + d] = part;
        }
    }
}

// gate/output epilogue: y = (part + D*u) * silu(z) -> bf16 hi/lo planes
__global__ __launch_bounds__(256) void gate_kernel(
    const float* __restrict__ xz,
    const float* __restrict__ u,
    const float* __restrict__ Dvec,
    u16* __restrict__ yhi, u16* __restrict__ ylo)
{
    int i4 = (blockIdx.x * 256 + threadIdx.x) * 4;
    if (i4 >= LSEQ * DINNER) return;
    int t = i4 / DINNER;
    int d = i4 - t * DINNER;
    size_t base = (size_t)t * (2 * DINNER) + d;
    float4 part = *(const float4*)&xz[base];
    float4 zv   = *(const float4*)&xz[base + DINNER];
    float4 uv   = *(const float4*)&u[i4];
    float4 Dd   = *(const float4*)&Dvec[d];
    float pa[4] = {part.x, part.y, part.z, part.w};
    float za[4] = {zv.x, zv.y, zv.z, zv.w};
    float ua[4] = {uv.x, uv.y, uv.z, uv.w};
    float Da[4] = {Dd.x, Dd.y, Dd.z, Dd.w};
    u16 ha[4], la[4];
#pragma unroll
    for (int j = 0; j < 4; ++j) {
        float sig = 1.f / (1.f + __expf(-za[j]));
        float yv = (pa[j] + Da[j] * ua[j]) * (za[j] * sig);
        ha[j] = f2bf_rn(yv);
        la[j] = f2bf_rn(yv - bf2f(ha[j]));
    }
    *(ushort4*)&yhi[i4] = make_ushort4(ha[0], ha[1], ha[2], ha[3]);
    *(ushort4*)&ylo[i4] = make_ushort4(la[0], la[1], la[2], la[3]);
}

// ---------------- launch ----------------
extern "C" void kernel_launch(void* const* d_in, const int* in_sizes, int n_in,
                              void* d_out, int out_size, void* d_ws, size_t ws_size,
                              hipStream_t stream) {
    const float* x          = (const float*)d_in[0];
    const float* in_proj_w  = (const float*)d_in[1];
    const float* conv_w     = (const float*)d_in[2];
    const float* conv_b     = (const float*)d_in[3];
    const float* x_proj_w   = (const float*)d_in[4];
    const float* dt_proj_w  = (const float*)d_in[5];
    const float* dt_proj_b  = (const float*)d_in[6];
    const float* A_log      = (const float*)d_in[7];
    const float* Dvec       = (const float*)d_in[8];
    const float* out_proj_w = (const float*)d_in[9];
    float* out = (float*)d_out;

    char* w = (char*)d_ws;
    auto alloc = [&](size_t bytes) { char* p = w; w += (bytes + 255) & ~(size_t)255; return p; };

    float* xz    = (float*)alloc((size_t)LSEQ * 2 * DINNER * 4);
    float* u     = (float*)alloc((size_t)LSEQ * DINNER * 4);
    float* xdbl  = (float*)alloc((size_t)LSEQ * XDBL_W * 4);
    float* dtb   = (float*)alloc((size_t)LSEQ * DINNER * 4);
    float* csum  = (float*)alloc((size_t)NCHUNK * DINNER * 4);
    float* S     = (float*)alloc((size_t)NCHUNK * NDN * 4);
    float* Ppart = (float*)alloc((size_t)SPLITK * LSEQ * XDBL_W * 4);
    u16* xhi  = (u16*)alloc((size_t)LSEQ * DMODEL * 2);
    u16* xlo  = (u16*)alloc((size_t)LSEQ * DMODEL * 2);
    u16* wihi = (u16*)alloc((size_t)2 * DINNER * DMODEL * 2);
    u16* wilo = (u16*)alloc((size_t)2 * DINNER * DMODEL * 2);
    u16* owhi = (u16*)alloc((size_t)DMODEL * DINNER * 2);
    u16* owlo = (u16*)alloc((size_t)DMODEL * DINNER * 2);
    u16* yhi  = (u16*)alloc((size_t)LSEQ * DINNER * 2);
    u16* ylo  = (u16*)alloc((size_t)LSEQ * DINNER * 2);
    float* opart = u;   // out_proj partials alias u..S (dead after gate_kernel)

    dim3 blk(256);

    // 0. fused conversions to bf16 hi/lo (one launch)
    {
        int n1 = 2 * DINNER * DMODEL;
        int n2 = DMODEL * DINNER;
        int n3 = LSEQ * DMODEL;
        cvt_all<<<(n1 + n2 + n3) / 1024, blk, 0, stream>>>(
            in_proj_w, wihi, wilo, n1, out_proj_w, owhi, owlo, n2, x, xhi, xlo);
    }

    // 1. xz = x @ in_proj_w.T   (M=2048, N=3072, K=768), 128x128 dbuf MFMA + XCD swizzle
    mfma_gemm_tn<128><<<dim3(LSEQ / 128, (2 * DINNER) / 128, 1), blk, 0, stream>>>(
        xhi, xlo, wihi, wilo, xz, 2 * DINNER, DMODEL, DMODEL);

    // 2. u = silu(depthwise_conv(xh) + b), 4 t/thread
    conv_silu_kernel<<<(LSEQ / 4) * DINNER / 256, blk, 0, stream>>>(xz, conv_w, conv_b, u);

    // 3. x_dbl = u @ x_proj_w.T (split-K fp32, deterministic reduce)
    gemm_tn_splitk<<<dim3(LSEQ / 64, (XDBL_W + 63) / 64, SPLITK), blk, 0, stream>>>(
        u, DINNER, x_proj_w, DINNER, Ppart, XDBL_W, LSEQ, XDBL_W, DINNER / SPLITK);
    splitk_reduce<<<(LSEQ * XDBL_W + 255) / 256, blk, 0, stream>>>(Ppart, xdbl, LSEQ * XDBL_W);

    // 4. dt = softplus(x_dbl[:, :48] @ dt_proj_w.T + dt_proj_b)
    gemm_tn<1><<<dim3(LSEQ / 64, DINNER / 64), blk, 0, stream>>>(
        xdbl, XDBL_W, dt_proj_w, DTRANK, dtb, DINNER, LSEQ, DINNER, DTRANK, dt_proj_b);

    // 5. chunked faithful selective scan (cumdt form); part -> xz cols 0..1535
    dt_chunksum<<<dim3(DINNER / 256, NCHUNK), blk, 0, stream>>>(dtb, csum);
    cumdt_excl<<<DINNER / 256, blk, 0, stream>>>(csum);
    scan_chunksum<<<dim3(DINNER / 16, NCHUNK), blk, 0, stream>>>(dtb, u, xdbl, A_log, csum, S);
    scan_exclusive<0><<<NDN / 256, blk, 0, stream>>>(S);
    scan_final<<<dim3(DINNER / 64, NCHUNK), blk, 0, stream>>>(
        dtb, u, xdbl, A_log, csum, S, xz);

    // 5b. gate epilogue
    gate_kernel<<<(LSEQ * DINNER) / 1024, blk, 0, stream>>>(xz, u, Dvec, yhi, ylo);

    // 6. out = y @ out_proj_w.T (128x64 tiles, split-K=4 + reduce) + XCD swizzle
    mfma_gemm_tn<64><<<dim3(LSEQ / 128, DMODEL / 64, OSPLIT), blk, 0, stream>>>(
        yhi, ylo, owhi, owlo, opart, DMODEL, DINNER, DINNER / OSPLIT);
    reduce4<<<(LSEQ * DMODEL) / 1024, blk, 0, stream>>>(opart, out, LSEQ * DMODEL);
}

// Round 23
// 214.757 us; speedup vs baseline: 1.0383x; 1.0036x over previous
//
#include <hip/hip_runtime.h>
#include <hip/hip_bf16.h>

// ---------------- sizes ----------------
#define LSEQ 2048
#define DMODEL 768
#define DINNER 1536
#define DSTATE 16
#define DTRANK 48
#define XDBL_W (DTRANK + 2*DSTATE)   // 80
#define CHUNK 32
#define NCHUNK (LSEQ / CHUNK)        // 64
#define NDN (DINNER * DSTATE)        // 24576
#define FEPS 1.1920928955078125e-07f
#define SPLITK 8
#define OSPLIT 4                     // split-K factor for out_proj
#define LDST2 36                     // padded LDS row stride (floats) for 32-t tiles

typedef short bf16x8 __attribute__((ext_vector_type(8)));
typedef float f32x4 __attribute__((ext_vector_type(4)));
typedef unsigned short u16;

__device__ __forceinline__ u16 f2bf_rn(float f) {
    unsigned u = __float_as_uint(f);
    unsigned r = u + 0x7FFFu + ((u >> 16) & 1u);
    return (u16)(r >> 16);
}
__device__ __forceinline__ float bf2f(u16 h) {
    return __uint_as_float(((unsigned)h) << 16);
}

// quad_perm DPP lane exchange (full-rate VALU, no LDS pipe).
template<int CTRL>
__device__ __forceinline__ float qperm(float x) {
    return __int_as_float(__builtin_amdgcn_update_dpp(
        0, __float_as_int(x), CTRL, 0xF, 0xF, true));
}

// ---------------- fused fp32 -> bf16 hi/lo split for all three arrays ----------------
__global__ __launch_bounds__(256) void cvt_all(
    const float* __restrict__ w_in,  u16* __restrict__ wihi, u16* __restrict__ wilo, int n1,
    const float* __restrict__ w_out, u16* __restrict__ owhi, u16* __restrict__ owlo, int n2,
    const float* __restrict__ x,     u16* __restrict__ xhi,  u16* __restrict__ xlo)
{
    int i4 = (blockIdx.x * 256 + threadIdx.x) * 4;
    const float* src; u16* hi; u16* lo; int off;
    if (i4 < n1)            { src = w_in;  hi = wihi; lo = wilo; off = i4; }
    else if (i4 < n1 + n2)  { src = w_out; hi = owhi; lo = owlo; off = i4 - n1; }
    else                    { src = x;     hi = xhi;  lo = xlo;  off = i4 - n1 - n2; }
    float4 v = *(const float4*)&src[off];
    u16 h0 = f2bf_rn(v.x), h1 = f2bf_rn(v.y), h2 = f2bf_rn(v.z), h3 = f2bf_rn(v.w);
    u16 l0 = f2bf_rn(v.x - bf2f(h0));
    u16 l1 = f2bf_rn(v.y - bf2f(h1));
    u16 l2 = f2bf_rn(v.z - bf2f(h2));
    u16 l3 = f2bf_rn(v.w - bf2f(h3));
    *(ushort4*)&hi[off] = make_ushort4(h0, h1, h2, h3);
    *(ushort4*)&lo[off] = make_ushort4(l0, l1, l2, l3);
}

// ---------------- split-bf16 MFMA GEMM, double-buffered, 128xBN tile ----------------
// XCD-aware bijective blockIdx swizzle (grid size % 8 == 0 in all uses).
template<int BN>
__global__ __launch_bounds__(256) void mfma_gemm_tn(
    const u16* __restrict__ Ahi, const u16* __restrict__ Alo,
    const u16* __restrict__ Bhi, const u16* __restrict__ Blo,
    float* __restrict__ C, int ldc, int ldk, int Klen)
{
    constexpr int BUFSZ = 8192 + BN * 64;   // u16 per buffer (A: 8192, B: BN*64)
    constexpr int NJ = BN / 32;             // acc columns per wave
    __shared__ u16 lds[2 * BUFSZ];
    const int tid = threadIdx.x;
    const int wid = tid >> 6;
    const int lane = tid & 63;

    // XCD swizzle: hw-consecutive blocks -> contiguous logical chunk per XCD
    int nwg = gridDim.x * gridDim.y * gridDim.z;
    int lin = (blockIdx.z * gridDim.y + blockIdx.y) * gridDim.x + blockIdx.x;
    int q = nwg >> 3;
    int swz = (lin & 7) * q + (lin >> 3);
    int bx = swz % gridDim.x;
    int tmp = swz / gridDim.x;
    int by = tmp % gridDim.y;
    int bz = tmp / gridDim.y;

    const int m0 = bx * 128;
    const int n0 = by * BN;
    const int Koff = bz * Klen;

    const int st_subrow = lane >> 2;
    const int st_cphys = lane & 3;
    const u16* myplane = (wid == 0) ? Ahi : (wid == 1) ? Alo : (wid == 2) ? Bhi : Blo;
    const int rowbase = (wid < 2) ? m0 : n0;
    const int nIss = (wid < 2) ? 8 : (BN / 16);
    const int planeOff = (wid < 2) ? wid * 4096 : 8192 + (wid - 2) * (BN * 32);

    f32x4 acc[4][NJ] = {};
    const int wm = (wid >> 1) * 64;
    const int wn = (wid & 1) * (BN / 2);
    const int fr = lane & 15;
    const int fc = lane >> 4;
    const int nsteps = Klen / 32;

    auto stage = [&](int buf, int k0) {
#pragma unroll
        for (int j = 0; j < 8; ++j) {
            if (j < nIss) {
                int row = j * 16 + st_subrow;
                int clog = st_cphys ^ ((row >> 1) & 3);
                const u16* g = myplane + (size_t)(rowbase + row) * ldk + k0 + clog * 8;
                u16* l = &lds[buf * BUFSZ + planeOff + j * 512];
                __builtin_amdgcn_global_load_lds(
                    (const __attribute__((address_space(1))) unsigned int*)g,
                    (__attribute__((address_space(3))) unsigned int*)l, 16, 0, 0);
            }
        }
    };

    stage(0, Koff);
    int cur = 0;
    for (int t = 0; t < nsteps; ++t) {
        __syncthreads();
        if (t + 1 < nsteps) stage(cur ^ 1, Koff + (t + 1) * 32);

        bf16x8 ah[4], al[4], bh[NJ], bl[NJ];
        const bf16x8* L = (const bf16x8*)&lds[cur * BUFSZ];
#pragma unroll
        for (int mi = 0; mi < 4; ++mi) {
            int r = wm + mi * 16 + fr;
            int idx = r * 4 + (fc ^ ((r >> 1) & 3));
            ah[mi] = L[idx];
            al[mi] = L[512 + idx];
        }
#pragma unroll
        for (int nj = 0; nj < NJ; ++nj) {
            int r = wn + nj * 16 + fr;
            int idx = r * 4 + (fc ^ ((r >> 1) & 3));
            bh[nj] = L[1024 + idx];
            bl[nj] = L[1024 + BN * 4 + idx];
        }
#pragma unroll
        for (int mi = 0; mi < 4; ++mi)
#pragma unroll
            for (int nj = 0; nj < NJ; ++nj) {
                acc[mi][nj] = __builtin_amdgcn_mfma_f32_16x16x32_bf16(ah[mi], bh[nj], acc[mi][nj], 0, 0, 0);
                acc[mi][nj] = __builtin_amdgcn_mfma_f32_16x16x32_bf16(ah[mi], bl[nj], acc[mi][nj], 0, 0, 0);
                acc[mi][nj] = __builtin_amdgcn_mfma_f32_16x16x32_bf16(al[mi], bh[nj], acc[mi][nj], 0, 0, 0);
            }
        cur ^= 1;
    }

    float* Cz = C + (size_t)bz * LSEQ * ldc;
#pragma unroll
    for (int mi = 0; mi < 4; ++mi) {
        int row_b = m0 + wm + mi * 16 + (lane >> 4) * 4;
#pragma unroll
        for (int nj = 0; nj < NJ; ++nj) {
            int col = n0 + wn + nj * 16 + (lane & 15);
#pragma unroll
            for (int r = 0; r < 4; ++r)
                Cz[(size_t)(row_b + r) * ldc + col] = acc[mi][nj][r];
        }
    }
}

// deterministic 4-way partial reduce for out_proj
__global__ __launch_bounds__(256) void reduce4(
    const float* __restrict__ Ppart, float* __restrict__ out, int n)
{
    int i = (blockIdx.x * 256 + threadIdx.x) * 4;
    if (i >= n) return;
    float4 a0 = *(const float4*)&Ppart[i];
    float4 a1 = *(const float4*)&Ppart[(size_t)n + i];
    float4 a2 = *(const float4*)&Ppart[(size_t)2 * n + i];
    float4 a3 = *(const float4*)&Ppart[(size_t)3 * n + i];
    float4 r;
    r.x = ((a0.x + a1.x) + a2.x) + a3.x;
    r.y = ((a0.y + a1.y) + a2.y) + a3.y;
    r.z = ((a0.z + a1.z) + a2.z) + a3.z;
    r.w = ((a0.w + a1.w) + a2.w) + a3.w;
    *(float4*)&out[i] = r;
}

// ---------------- fp32 tiled GEMM (dt_proj) ----------------
template<int EPI>
__global__ __launch_bounds__(256) void gemm_tn(
    const float* __restrict__ A, int lda,
    const float* __restrict__ B, int ldb,
    float* __restrict__ C, int ldc,
    int M, int N, int K,
    const float* __restrict__ bias)
{
    __shared__ float As[16][64 + 4];
    __shared__ float Bs[16][64 + 4];
    const int tid = threadIdx.x;
    const int m0 = blockIdx.x * 64;
    const int n0 = blockIdx.y * 64;
    const int tx = tid & 15;
    const int ty = tid >> 4;
    const int lr = tid >> 4;
    const int lc = tid & 15;
    float acc[4][4] = {};

    for (int k0 = 0; k0 < K; k0 += 16) {
        const int k = k0 + lc;
#pragma unroll
        for (int i = 0; i < 4; ++i) {
            int m = m0 + lr + i * 16;
            As[lc][lr + i * 16] = (m < M) ? A[(size_t)m * lda + k] : 0.f;
        }
#pragma unroll
        for (int i = 0; i < 4; ++i) {
            int n = n0 + lr + i * 16;
            Bs[lc][lr + i * 16] = (n < N) ? B[(size_t)n * ldb + k] : 0.f;
        }
        __syncthreads();
#pragma unroll
        for (int kk = 0; kk < 16; ++kk) {
            float a[4], b[4];
#pragma unroll
            for (int i = 0; i < 4; ++i) a[i] = As[kk][ty * 4 + i];
#pragma unroll
            for (int j = 0; j < 4; ++j) b[j] = Bs[kk][tx * 4 + j];
#pragma unroll
            for (int i = 0; i < 4; ++i)
#pragma unroll
                for (int j = 0; j < 4; ++j)
                    acc[i][j] = fmaf(a[i], b[j], acc[i][j]);
        }
        __syncthreads();
    }

#pragma unroll
    for (int i = 0; i < 4; ++i) {
        int m = m0 + ty * 4 + i;
        if (m >= M) continue;
#pragma unroll
        for (int j = 0; j < 4; ++j) {
            int n = n0 + tx * 4 + j;
            if (n >= N) continue;
            float v = acc[i][j];
            if (EPI == 1) {
                v += bias[n];
                v = fmaxf(v, 0.f) + log1pf(expf(-fabsf(v)));
            }
            C[(size_t)m * ldc + n] = v;
        }
    }
}

// ---------------- fp32 split-K GEMM for x_proj ----------------
__global__ __launch_bounds__(256) void gemm_tn_splitk(
    const float* __restrict__ A, int lda,
    const float* __restrict__ B, int ldb,
    float* __restrict__ Cpart, int ldc,
    int M, int N, int Kchunk)
{
    __shared__ float As[16][64 + 4];
    __shared__ float Bs[16][64 + 4];
    const int tid = threadIdx.x;
    const int m0 = blockIdx.x * 64;
    const int n0 = blockIdx.y * 64;
    const int kb = blockIdx.z * Kchunk;
    const int tx = tid & 15;
    const int ty = tid >> 4;
    const int lr = tid >> 4;
    const int lc = tid & 15;
    float acc[4][4] = {};

    for (int k0 = kb; k0 < kb + Kchunk; k0 += 16) {
        const int k = k0 + lc;
#pragma unroll
        for (int i = 0; i < 4; ++i) {
            int m = m0 + lr + i * 16;
            As[lc][lr + i * 16] = (m < M) ? A[(size_t)m * lda + k] : 0.f;
        }
#pragma unroll
        for (int i = 0; i < 4; ++i) {
            int n = n0 + lr + i * 16;
            Bs[lc][lr + i * 16] = (n < N) ? B[(size_t)n * ldb + k] : 0.f;
        }
        __syncthreads();
#pragma unroll
        for (int kk = 0; kk < 16; ++kk) {
            float a[4], b[4];
#pragma unroll
            for (int i = 0; i < 4; ++i) a[i] = As[kk][ty * 4 + i];
#pragma unroll
            for (int j = 0; j < 4; ++j) b[j] = Bs[kk][tx * 4 + j];
#pragma unroll
            for (int i = 0; i < 4; ++i)
#pragma unroll
                for (int j = 0; j < 4; ++j)
                    acc[i][j] = fmaf(a[i], b[j], acc[i][j]);
        }
        __syncthreads();
    }

    float* Cs = Cpart + (size_t)blockIdx.z * M * ldc;
#pragma unroll
    for (int i = 0; i < 4; ++i) {
        int m = m0 + ty * 4 + i;
        if (m >= M) continue;
#pragma unroll
        for (int j = 0; j < 4; ++j) {
            int n = n0 + tx * 4 + j;
            if (n >= N) continue;
            Cs[(size_t)m * ldc + n] = acc[i][j];
        }
    }
}

__global__ __launch_bounds__(256) void splitk_reduce(
    const float* __restrict__ Ppart, float* __restrict__ out, int n)
{
    int i = blockIdx.x * 256 + threadIdx.x;
    if (i >= n) return;
    float s = 0.f;
#pragma unroll
    for (int z = 0; z < SPLITK; ++z) s += Ppart[(size_t)z * n + i];
    out[i] = s;
}

// ---------------- depthwise causal conv1d (width 4) + SiLU, 4 t-steps/thread ----------------
__global__ __launch_bounds__(256) void conv_silu_kernel(
    const float* __restrict__ xz,
    const float* __restrict__ conv_w,
    const float* __restrict__ conv_b,
    float* __restrict__ u)
{
    int idx = blockIdx.x * 256 + threadIdx.x;
    int d = idx % DINNER;
    int t0 = (idx / DINNER) * 4;
    float w[4];
#pragma unroll
    for (int j = 0; j < 4; ++j) w[j] = conv_w[d * 4 + j];
    const float b = conv_b[d];
    float xv[7];
#pragma unroll
    for (int k = 0; k < 7; ++k) {
        int s = t0 - 3 + k;
        xv[k] = (s >= 0) ? xz[(size_t)s * (2 * DINNER) + d] : 0.f;
    }
#pragma unroll
    for (int i = 0; i < 4; ++i) {
        float acc = b;
#pragma unroll
        for (int j = 0; j < 4; ++j)
            acc = fmaf(xv[i + j], w[j], acc);
        float sig = 1.f / (1.f + __expf(-acc));
        u[(size_t)(t0 + i) * DINNER + d] = acc * sig;
    }
}

// ================= chunked faithful scan (CHUNK=32, cumdt form) =================
// Per-chunk dt sums (d-only, 16x less work than old chunkprod).
__global__ __launch_bounds__(256) void dt_chunksum(
    const float* __restrict__ dtm, float* __restrict__ csum)
{
    int d = blockIdx.x * 256 + threadIdx.x;          // gridDim.x = DINNER/256
    int c = blockIdx.y;
    size_t base = (size_t)c * CHUNK * DINNER + d;
    float s = 0.f;
#pragma unroll
    for (int i = 0; i < CHUNK; ++i)
        s += dtm[base + (size_t)i * DINNER];
    csum[(size_t)c * DINNER + d] = s;
}

// Exclusive sum over chunks of csum (register-staged).
__global__ __launch_bounds__(256) void cumdt_excl(float* __restrict__ csum)
{
    int d = blockIdx.x * 256 + threadIdx.x;
    float v[NCHUNK];
#pragma unroll
    for (int c = 0; c < NCHUNK; ++c)
        v[c] = csum[(size_t)c * DINNER + d];
    float run = 0.f;
#pragma unroll
    for (int c = 0; c < NCHUNK; ++c) {
        float t = v[c];
        v[c] = run;
        run += t;
    }
#pragma unroll
    for (int c = 0; c < NCHUNK; ++c)
        csum[(size_t)c * DINNER + d] = v[c];
}

// Register-staged exclusive scan over chunks for S (g), n-dependent.
template<int PROD>
__global__ __launch_bounds__(256) void scan_exclusive(float* __restrict__ buf)
{
    const int dn = blockIdx.x * 256 + threadIdx.x;
    float v[NCHUNK];
#pragma unroll
    for (int c = 0; c < NCHUNK; ++c)
        v[c] = buf[(size_t)c * NDN + dn];
    float run = PROD ? 1.f : 0.f;
#pragma unroll
    for (int c = 0; c < NCHUNK; ++c) {
        float t = v[c];
        v[c] = run;
        run = PROD ? run * t : run + t;
    }
#pragma unroll
    for (int c = 0; c < NCHUNK; ++c)
        buf[(size_t)c * NDN + dn] = v[c];
}

// Phase 3a: prefix-sum-exp form, seeded by cumdt (p = exp(Acoef*(cumdt + local))).
__global__ __launch_bounds__(256) void scan_chunksum(
    const float* __restrict__ dtm,
    const float* __restrict__ u,
    const float* __restrict__ xdbl,
    const float* __restrict__ A_log,
    const float* __restrict__ cumdt,
    float* __restrict__ S)
{
    __shared__ float sdtT[16][LDST2], sduT[16][LDST2], sBT[16][LDST2];
    const int tid = threadIdx.x;
    const int d0 = blockIdx.x * 16;
    const int t0 = blockIdx.y * CHUNK;
    const int r = tid >> 4, c = tid & 15;
#pragma unroll
    for (int i = 0; i < 2; ++i) {
        int t = r + i * 16;
        size_t row = (size_t)(t0 + t);
        float dtv = dtm[row * DINNER + d0 + c];
        sdtT[c][t] = dtv;
        sduT[c][t] = dtv * u[row * DINNER + d0 + c];
        sBT[c][t]  = xdbl[row * XDBL_W + DTRANK + c];
    }
    __syncthreads();
    const int n = tid & 15, dl = tid >> 4;
    const float Acoef = -expf(A_log[(d0 + dl) * DSTATE + n]);
    float s = cumdt[(size_t)blockIdx.y * DINNER + d0 + dl];
    float acc = 0.f;
#pragma unroll
    for (int tb = 0; tb < CHUNK / 4; ++tb) {
        f32x4 dq  = *(const f32x4*)&sdtT[dl][tb * 4];
        f32x4 duq = *(const f32x4*)&sduT[dl][tb * 4];
        f32x4 bq  = *(const f32x4*)&sBT[n][tb * 4];
#pragma unroll
        for (int j = 0; j < 4; ++j) {
            s += dq[j];
            float p = __expf(Acoef * s);
            acc += __fdividef(duq[j] * bq[j], fmaxf(p, FEPS));
        }
    }
    S[(size_t)blockIdx.y * NDN + d0 * DSTATE + tid] = acc;
}

// Phase 3c: 4-n-per-lane + cumdt-seeded prefix-sum-exp + quad-DPP reduction.
__global__ __launch_bounds__(256) void scan_final(
    const float* __restrict__ dtm,
    const float* __restrict__ u,
    const float* __restrict__ xdbl,
    const float* __restrict__ A_log,
    const float* __restrict__ cumdt,
    const float* __restrict__ Gpre,
    float* __restrict__ xz)           // part written to cols 0..1535
{
    __shared__ float sdtT[64][LDST2], sduT[64][LDST2];
    __shared__ float sBT[16][LDST2], sCT[16][LDST2];
    const int tid = threadIdx.x;
    const int d0 = blockIdx.x * 64;
    const int t0 = blockIdx.y * CHUNK;

#pragma unroll
    for (int i = 0; i < 8; ++i) {
        int idx = i * 256 + tid;
        int dl = idx & 63, tl = idx >> 6;
        size_t row = (size_t)(t0 + tl);
        float dtv = dtm[row * DINNER + d0 + dl];
        sdtT[dl][tl] = dtv;
        sduT[dl][tl] = dtv * u[row * DINNER + d0 + dl];
    }
#pragma unroll
    for (int i = 0; i < 2; ++i) {
        int idx = i * 256 + tid;
        int n = idx & 15, tl = idx >> 4;
        size_t row = (size_t)(t0 + tl);
        sBT[n][tl] = xdbl[row * XDBL_W + DTRANK + n];
        sCT[n][tl] = xdbl[row * XDBL_W + DTRANK + DSTATE + n];
    }
    __syncthreads();

    const int lane = tid & 63, wid = tid >> 6;
    const int dloc = wid * 16 + (lane >> 2);
    const int d = d0 + dloc;
    const int nq = lane & 3;

    f32x4 Ar = *(const f32x4*)&A_log[d * DSTATE + nq * 4];
    float Ac[4] = {-expf(Ar[0]), -expf(Ar[1]), -expf(Ar[2]), -expf(Ar[3])};
    size_t pgbase = (size_t)blockIdx.y * NDN + (size_t)d * DSTATE + nq * 4;
    f32x4 g = *(const f32x4*)&Gpre[pgbase];
    float s = cumdt[(size_t)blockIdx.y * DINNER + d];

#pragma unroll
    for (int tb = 0; tb < CHUNK / 4; ++tb) {
        f32x4 dq  = *(const f32x4*)&sdtT[dloc][tb * 4];
        f32x4 duq = *(const f32x4*)&sduT[dloc][tb * 4];
        f32x4 b0 = *(const f32x4*)&sBT[nq * 4 + 0][tb * 4];
        f32x4 b1 = *(const f32x4*)&sBT[nq * 4 + 1][tb * 4];
        f32x4 b2 = *(const f32x4*)&sBT[nq * 4 + 2][tb * 4];
        f32x4 b3 = *(const f32x4*)&sBT[nq * 4 + 3][tb * 4];
        f32x4 c0 = *(const f32x4*)&sCT[nq * 4 + 0][tb * 4];
        f32x4 c1 = *(const f32x4*)&sCT[nq * 4 + 1][tb * 4];
        f32x4 c2 = *(const f32x4*)&sCT[nq * 4 + 2][tb * 4];
        f32x4 c3 = *(const f32x4*)&sCT[nq * 4 + 3][tb * 4];
#pragma unroll
        for (int j = 0; j < 4; ++j) {
            float duv = duq[j];
            s += dq[j];
            float p0 = __expf(Ac[0] * s);
            float p1 = __expf(Ac[1] * s);
            float p2 = __expf(Ac[2] * s);
            float p3 = __expf(Ac[3] * s);
            g[0] += __fdividef(duv * b0[j], fmaxf(p0, FEPS));
            g[1] += __fdividef(duv * b1[j], fmaxf(p1, FEPS));
            g[2] += __fdividef(duv * b2[j], fmaxf(p2, FEPS));
            g[3] += __fdividef(duv * b3[j], fmaxf(p3, FEPS));
            float part = (g[0] * p0) * c0[j];
            part = fmaf(g[1] * p1, c1[j], part);
            part = fmaf(g[2] * p2, c2[j], part);
            part = fmaf(g[3] * p3, c3[j], part);
            part += qperm<0xB1>(part);
            part += qperm<0x4E>(part);
            if (nq == 0)
                xz[(size_t)(t0 + tb * 4 + j) * (2 * DINNER) + d] = part;
        }
    }
}

// gate/output epilogue: y = (part + D*u) * silu(z) -> bf16 hi/lo planes
__global__ __launch_bounds__(256) void gate_kernel(
    const float* __restrict__ xz,
    const float* __restrict__ u,
    const float* __restrict__ Dvec,
    u16* __restrict__ yhi, u16* __restrict__ ylo)
{
    int i4 = (blockIdx.x * 256 + threadIdx.x) * 4;
    if (i4 >= LSEQ * DINNER) return;
    int t = i4 / DINNER;
    int d = i4 - t * DINNER;
    size_t base = (size_t)t * (2 * DINNER) + d;
    float4 part = *(const float4*)&xz[base];
    float4 zv   = *(const float4*)&xz[base + DINNER];
    float4 uv   = *(const float4*)&u[i4];
    float4 Dd   = *(const float4*)&Dvec[d];
    float pa[4] = {part.x, part.y, part.z, part.w};
    float za[4] = {zv.x, zv.y, zv.z, zv.w};
    float ua[4] = {uv.x, uv.y, uv.z, uv.w};
    float Da[4] = {Dd.x, Dd.y, Dd.z, Dd.w};
    u16 ha[4], la[4];
#pragma unroll
    for (int j = 0; j < 4; ++j) {
        float sig = 1.f / (1.f + __expf(-za[j]));
        float yv = (pa[j] + Da[j] * ua[j]) * (za[j] * sig);
        ha[j] = f2bf_rn(yv);
        la[j] = f2bf_rn(yv - bf2f(ha[j]));
    }
    *(ushort4*)&yhi[i4] = make_ushort4(ha[0], ha[1], ha[2], ha[3]);
    *(ushort4*)&ylo[i4] = make_ushort4(la[0], la[1], la[2], la[3]);
}

// ---------------- launch ----------------
extern "C" void kernel_launch(void* const* d_in, const int* in_sizes, int n_in,
                              void* d_out, int out_size, void* d_ws, size_t ws_size,
                              hipStream_t stream) {
    const float* x          = (const float*)d_in[0];
    const float* in_proj_w  = (const float*)d_in[1];
    const float* conv_w     = (const float*)d_in[2];
    const float* conv_b     = (const float*)d_in[3];
    const float* x_proj_w   = (const float*)d_in[4];
    const float* dt_proj_w  = (const float*)d_in[5];
    const float* dt_proj_b  = (const float*)d_in[6];
    const float* A_log      = (const float*)d_in[7];
    const float* Dvec       = (const float*)d_in[8];
    const float* out_proj_w = (const float*)d_in[9];
    float* out = (float*)d_out;

    char* w = (char*)d_ws;
    auto alloc = [&](size_t bytes) { char* p = w; w += (bytes + 255) & ~(size_t)255; return p; };

    float* xz    = (float*)alloc((size_t)LSEQ * 2 * DINNER * 4);
    float* u     = (float*)alloc((size_t)LSEQ * DINNER * 4);
    float* xdbl  = (float*)alloc((size_t)LSEQ * XDBL_W * 4);
    float* dtb   = (float*)alloc((size_t)LSEQ * DINNER * 4);
    float* csum  = (float*)alloc((size_t)NCHUNK * DINNER * 4);
    float* S     = (float*)alloc((size_t)NCHUNK * NDN * 4);
    float* Ppart = (float*)alloc((size_t)SPLITK * LSEQ * XDBL_W * 4);
    u16* xhi  = (u16*)alloc((size_t)LSEQ * DMODEL * 2);
    u16* xlo  = (u16*)alloc((size_t)LSEQ * DMODEL * 2);
    u16* wihi = (u16*)alloc((size_t)2 * DINNER * DMODEL * 2);
    u16* wilo = (u16*)alloc((size_t)2 * DINNER * DMODEL * 2);
    u16* owhi = (u16*)alloc((size_t)DMODEL * DINNER * 2);
    u16* owlo = (u16*)alloc((size_t)DMODEL * DINNER * 2);
    u16* yhi  = (u16*)alloc((size_t)LSEQ * DINNER * 2);
    u16* ylo  = (u16*)alloc((size_t)LSEQ * DINNER * 2);
    float* opart = u;   // out_proj partials alias u..S (dead after gate_kernel)

    dim3 blk(256);

    // 0. fused conversions to bf16 hi/lo (one launch)
    {
        int n1 = 2 * DINNER * DMODEL;
        int n2 = DMODEL * DINNER;
        int n3 = LSEQ * DMODEL;
        cvt_all<<<(n1 + n2 + n3) / 1024, blk, 0, stream>>>(
            in_proj_w, wihi, wilo, n1, out_proj_w, owhi, owlo, n2, x, xhi, xlo);
    }

    // 1. xz = x @ in_proj_w.T   (M=2048, N=3072, K=768), 128x128 dbuf MFMA + XCD swizzle
    mfma_gemm_tn<128><<<dim3(LSEQ / 128, (2 * DINNER) / 128, 1), blk, 0, stream>>>(
        xhi, xlo, wihi, wilo, xz, 2 * DINNER, DMODEL, DMODEL);

    // 2. u = silu(depthwise_conv(xh) + b), 4 t/thread
    conv_silu_kernel<<<(LSEQ / 4) * DINNER / 256, blk, 0, stream>>>(xz, conv_w, conv_b, u);

    // 3. x_dbl = u @ x_proj_w.T (split-K fp32, deterministic reduce)
    gemm_tn_splitk<<<dim3(LSEQ / 64, (XDBL_W + 63) / 64, SPLITK), blk, 0, stream>>>(
        u, DINNER, x_proj_w, DINNER, Ppart, XDBL_W, LSEQ, XDBL_W, DINNER / SPLITK);
    splitk_reduce<<<(LSEQ * XDBL_W + 255) / 256, blk, 0, stream>>>(Ppart, xdbl, LSEQ * XDBL_W);

    // 4. dt = softplus(x_dbl[:, :48] @ dt_proj_w.T + dt_proj_b)
    gemm_tn<1><<<dim3(LSEQ / 64, DINNER / 64), blk, 0, stream>>>(
        xdbl, XDBL_W, dt_proj_w, DTRANK, dtb, DINNER, LSEQ, DINNER, DTRANK, dt_proj_b);

    // 5. chunked faithful selective scan (cumdt form); part -> xz cols 0..1535
    dt_chunksum<<<dim3(DINNER / 256, NCHUNK), blk, 0, stream>>>(dtb, csum);
    cumdt_excl<<<DINNER / 256, blk, 0, stream>>>(csum);
    scan_chunksum<<<dim3(DINNER / 16, NCHUNK), blk, 0, stream>>>(dtb, u, xdbl, A_log, csum, S);
    scan_exclusive<0><<<NDN / 256, blk, 0, stream>>>(S);
    scan_final<<<dim3(DINNER / 64, NCHUNK), blk, 0, stream>>>(
        dtb, u, xdbl, A_log, csum, S, xz);

    // 5b. gate epilogue
    gate_kernel<<<(LSEQ * DINNER) / 1024, blk, 0, stream>>>(xz, u, Dvec, yhi, ylo);

    // 6. out = y @ out_proj_w.T (128x64 tiles, split-K=4 + reduce) + XCD swizzle
    mfma_gemm_tn<64><<<dim3(LSEQ / 128, DMODEL / 64, OSPLIT), blk, 0, stream>>>(
        yhi, ylo, owhi, owlo, opart, DMODEL, DINNER, DINNER / OSPLIT);
    reduce4<<<(LSEQ * DMODEL) / 1024, blk, 0, stream>>>(opart, out, LSEQ * DMODEL);
}